// Round 8
// baseline (579.976 us; speedup 1.0000x reference)
//
#include <hip/hip_runtime.h>
#include <math.h>

// ---------- types ----------
typedef __attribute__((ext_vector_type(4))) float f32x4;
typedef __attribute__((ext_vector_type(16))) float f32x16;
typedef __attribute__((ext_vector_type(4))) unsigned int u32x4;
typedef __attribute__((ext_vector_type(2))) unsigned int u32x2;
typedef __attribute__((ext_vector_type(8))) unsigned short u16x8;
typedef __attribute__((ext_vector_type(4))) unsigned short u16x4;
typedef __attribute__((ext_vector_type(8))) __bf16 bf16x8;

union F8 { u32x4 u; u16x8 us; bf16x8 v; };

#define LOG2E 1.4426950408889634f

__device__ __forceinline__ unsigned short f2bf(float f) {
  unsigned int u = __float_as_uint(f);
  u += 0x7fffu + ((u >> 16) & 1u);
  return (unsigned short)(u >> 16);
}
__device__ __forceinline__ float bf2f(unsigned short s) {
  return __uint_as_float(((unsigned int)s) << 16);
}

// async global->LDS, 16B per lane; lds dest = wave-uniform base + lane*16
__device__ __forceinline__ void ldsload16(const void* g, void* l) {
  __builtin_amdgcn_global_load_lds((const __attribute__((address_space(1))) unsigned int*)g,
                                   (__attribute__((address_space(3))) unsigned int*)l, 16, 0, 0);
}

// ---------- all weight transposes in one launch ----------
// in fp32 (K x N) -> out bf16 (row' x K); remap=s>0: row' = ((n>>s)<<(s+1))+(n&((1<<s)-1))+radd
struct WTDesc {
  const float* in;
  unsigned short* out;
  int K, N, remap, radd, tiles;
};
struct WTArgs { WTDesc d[8]; };

__global__ __launch_bounds__(256) void wtrans_all(WTArgs a) {
  __shared__ float tile[32][33];
  int t = blockIdx.x, i = 0;
  while (t >= a.d[i].tiles) { t -= a.d[i].tiles; i++; }
  const float* in = a.d[i].in;
  unsigned short* out = a.d[i].out;
  int K = a.d[i].K, N = a.d[i].N, remap = a.d[i].remap, radd = a.d[i].radd;
  int ntx = N >> 5;
  int n0 = (t % ntx) * 32, k0 = (t / ntx) * 32;
  int tx = threadIdx.x & 31, ty = threadIdx.x >> 5;
#pragma unroll
  for (int s = 0; s < 32; s += 8)
    tile[ty + s][tx] = in[(size_t)(k0 + ty + s) * N + n0 + tx];
  __syncthreads();
#pragma unroll
  for (int s = 0; s < 32; s += 8) {
    int n = n0 + ty + s;
    int rowp = remap ? (((n >> remap) << (remap + 1)) + (n & ((1 << remap) - 1)) + radd) : n;
    out[(size_t)rowp * K + k0 + tx] = f2bf(tile[tx][ty + s]);
  }
}

// ---------- flat fp32 -> bf16 ----------
__global__ __launch_bounds__(256) void f2bf_copy(const float* __restrict__ in,
                                                 unsigned short* __restrict__ out, int n) {
  int i = (blockIdx.x * 256 + threadIdx.x) * 4;
  if (i < n) {
    f32x4 v = *(const f32x4*)(in + i);
    u16x4 o;
#pragma unroll
    for (int j = 0; j < 4; j++) o[j] = f2bf(v[j]);
    *(u16x4*)(out + i) = o;
  }
}

// ---------- mods = silu(t_mod) @ adaLN_W + adaLN_b ; (B x 6144) fp32 ----------
// split-k: block covers 64 cols x 4 k-groups of 256; grid (96, 2) = 192 blocks.
__global__ __launch_bounds__(256) void mods_kernel(const float* __restrict__ t_mod,
                                                   const float* __restrict__ W,
                                                   const float* __restrict__ bias,
                                                   float* __restrict__ mods) {
  int b = blockIdx.y;
  int tid = threadIdx.x;
  int j = blockIdx.x * 64 + (tid & 63);
  int kg = tid >> 6;
  __shared__ float a_s[1024];
  __shared__ float red[4][64];
  for (int i = tid; i < 1024; i += 256) {
    float tv = t_mod[b * 1024 + i];
    a_s[i] = tv / (1.0f + expf(-tv));
  }
  __syncthreads();
  float acc = 0.0f;
  int k0 = kg * 256;
  for (int k = k0; k < k0 + 256; k++) acc = fmaf(a_s[k], W[(size_t)k * 6144 + j], acc);
  red[kg][tid & 63] = acc;
  __syncthreads();
  if (kg == 0) {
    float s = red[0][tid] + red[1][tid] + red[2][tid] + red[3][tid] + bias[j];
    mods[b * 6144 + j] = s;
  }
}

// ---------- rmsnorm (+ optional adaLN modulation), fp32 in -> bf16 out ----------
__global__ __launch_bounds__(256) void rmsnorm_mod(const float* __restrict__ x,
                                                   const float* __restrict__ w,
                                                   const float* mods, int shift_off,
                                                   int scale_off,
                                                   unsigned short* __restrict__ out) {
  int row = blockIdx.x;
  int b = row >> 11;
  const float* xr = x + (size_t)row * 1024;
  int t = threadIdx.x;
  f32x4 xv = *(const f32x4*)(xr + t * 4);
  float ss = xv[0] * xv[0] + xv[1] * xv[1] + xv[2] * xv[2] + xv[3] * xv[3];
#pragma unroll
  for (int off = 32; off >= 1; off >>= 1) ss += __shfl_xor(ss, off, 64);
  __shared__ float red[4];
  if ((t & 63) == 0) red[t >> 6] = ss;
  __syncthreads();
  float tot = red[0] + red[1] + red[2] + red[3];
  float rr = rsqrtf(tot * (1.0f / 1024.0f) + 1e-6f);
  f32x4 wv = *(const f32x4*)(w + t * 4);
  f32x4 scv = (f32x4)(0.0f), shv = (f32x4)(0.0f);
  if (mods) {
    scv = *(const f32x4*)(mods + b * 6144 + scale_off + t * 4);
    shv = *(const f32x4*)(mods + b * 6144 + shift_off + t * 4);
  }
  u16x4 ov;
#pragma unroll
  for (int j = 0; j < 4; j++) {
    float n = xv[j] * rr * wv[j];
    ov[j] = f2bf(n * (1.0f + scv[j]) + shv[j]);
  }
  *(u16x4*)(out + (size_t)row * 1024 + t * 4) = ov;
}

// ---------- pipelined GEMM: C = A(MxK,bf16,lda) * Bt(NxK,bf16)^T ----------
// TM in {128, 64}. 4 LDS bufs, 3-tile lookahead, counted vmcnt, lgkmcnt(0)
// folded pre-barrier, chunk-XOR swizzle both sides -> conflict-free ds_read_b128.
// EPI 0: bf16 store. EPI 1: fp32 out = res + gate*acc. EPI 3: bf16 + RoPE cols<2048.
template <int EPI, int TM>
__global__ __launch_bounds__(256) void gemm_pipe(const unsigned short* __restrict__ A,
                                                 const unsigned short* __restrict__ Bt,
                                                 void* Cout, const float* res,
                                                 const float* gate, const float* fcos,
                                                 const float* fsin, int N, int K, int lda) {
  constexpr int BUF = TM * 64 + 8192;  // bytes per buffer (A tile + B tile)
  constexpr int TN = (TM == 128) ? 2 : 1;
  __shared__ char smem[4 * BUF];
  int tid = threadIdx.x;
  int wave = tid >> 6, lane = tid & 63;
  int row0 = blockIdx.x * TM, col0 = blockIdx.y * 128;
  int wm = (TM == 128) ? (wave & 1) * 64 : 0;
  int wn = (TM == 128) ? (wave >> 1) * 64 : wave * 32;
  int ln31 = lane & 31, lk5 = lane >> 5;
  int cxor = ln31 & 3;
  int co[2];
#pragma unroll
  for (int ks = 0; ks < 2; ks++) co[ks] = ((lk5 + 2 * ks) ^ cxor) * 8;

  // staging: thread slot covers row srow, 16B chunk schunk (XOR'd by row&3)
  int srow = tid >> 2;
  int schunk = (tid & 3) ^ ((tid >> 2) & 3);
  const unsigned short* aB = A + (size_t)(row0 + srow) * lda + schunk * 8;
  const unsigned short* bB = Bt + (size_t)(col0 + srow) * K + schunk * 8;

#define STAGEP(kt, bi)                                                       \
  {                                                                          \
    char* dA = smem + (bi) * BUF + wave * 1024;                              \
    char* dB = smem + (bi) * BUF + TM * 64 + wave * 1024;                    \
    const unsigned short* sa_ = aB + (kt) * 32;                              \
    const unsigned short* sb_ = bB + (kt) * 32;                              \
    ldsload16(sa_, dA);                                                      \
    if constexpr (TM == 128) ldsload16(sa_ + 64 * (size_t)lda, dA + 4096);   \
    ldsload16(sb_, dB);                                                      \
    ldsload16(sb_ + 64 * (size_t)K, dB + 4096);                              \
  }

  f32x16 acc[2][TN];
#pragma unroll
  for (int i = 0; i < 2; i++)
#pragma unroll
    for (int j = 0; j < TN; j++) acc[i][j] = (f32x16)(0.0f);

  int nk = K >> 5;
  STAGEP(0, 0);
  STAGEP(1, 1);
  STAGEP(2, 2);

  for (int t = 0; t < nk; t++) {
    if constexpr (TM == 128)
      asm volatile("s_waitcnt vmcnt(8) lgkmcnt(0)\n\ts_barrier" ::: "memory");
    else
      asm volatile("s_waitcnt vmcnt(6) lgkmcnt(0)\n\ts_barrier" ::: "memory");
    int kt3 = t + 3;
    if (kt3 >= nk) kt3 -= nk;  // tail: dummy restage (unread), uniform count
    STAGEP(kt3, (t + 3) & 3);
    const unsigned short* As = (const unsigned short*)(smem + (t & 3) * BUF);
    const unsigned short* Bs = (const unsigned short*)(smem + (t & 3) * BUF + TM * 64);
    bf16x8 af[2][2], bfr[TN][2];
#pragma unroll
    for (int ti = 0; ti < 2; ti++)
#pragma unroll
      for (int ks = 0; ks < 2; ks++)
        af[ti][ks] = *(const bf16x8*)&As[(wm + ti * 32 + ln31) * 32 + co[ks]];
#pragma unroll
    for (int tj = 0; tj < TN; tj++)
#pragma unroll
      for (int ks = 0; ks < 2; ks++)
        bfr[tj][ks] = *(const bf16x8*)&Bs[(wn + tj * 32 + ln31) * 32 + co[ks]];
    __builtin_amdgcn_s_setprio(1);
#pragma unroll
    for (int ks = 0; ks < 2; ks++)
#pragma unroll
      for (int ti = 0; ti < 2; ti++)
#pragma unroll
        for (int tj = 0; tj < TN; tj++)
          acc[ti][tj] = __builtin_amdgcn_mfma_f32_32x32x16_bf16(af[ti][ks], bfr[tj][ks],
                                                                acc[ti][tj], 0, 0, 0);
    __builtin_amdgcn_s_setprio(0);
  }
  asm volatile("s_waitcnt vmcnt(0) lgkmcnt(0)\n\ts_barrier" ::: "memory");

  float(*eps)[132] = (float(*)[132])smem;
  int tr = tid >> 3, tc = (tid & 7) * 8;
  constexpr int NPASS = (TM == 128) ? 4 : 2;
#pragma unroll
  for (int p = 0; p < NPASS; p++) {
    __syncthreads();
    if constexpr (TM == 128) {
      if ((wave & 1) == (p >> 1)) {
        int ti = p & 1;
#pragma unroll
        for (int tj = 0; tj < TN; tj++)
#pragma unroll
          for (int rg = 0; rg < 16; rg++) {
            int rl = (rg & 3) + 8 * (rg >> 2) + 4 * (lane >> 5);
            eps[rl][wn + tj * 32 + ln31] = acc[ti][tj][rg];
          }
      }
    } else {
#pragma unroll
      for (int rg = 0; rg < 16; rg++) {
        int rl = (rg & 3) + 8 * (rg >> 2) + 4 * (lane >> 5);
        eps[rl][wn + ln31] = acc[p][0][rg];
      }
    }
    __syncthreads();
    int grow = row0 + p * 32 + tr;
    if (EPI == 0 || EPI == 3) {
      bool rope = (EPI == 3) && (col0 < 2048);
      int l = grow & 2047;
#pragma unroll
      for (int c = tc; c < 128; c += 64) {
        f32x4 v0 = *(const f32x4*)&eps[tr][c];
        f32x4 v1 = *(const f32x4*)&eps[tr][c + 4];
        if (rope) {
          int d2 = ((col0 + c) & 63) >> 1;
          f32x4 cs = *(const f32x4*)(fcos + l * 32 + d2);
          f32x4 sn = *(const f32x4*)(fsin + l * 32 + d2);
          float a0 = v0[0], a1 = v0[1], a2 = v0[2], a3 = v0[3];
          v0[0] = a0 * cs[0] - a1 * sn[0];
          v0[1] = a0 * sn[0] + a1 * cs[0];
          v0[2] = a2 * cs[1] - a3 * sn[1];
          v0[3] = a2 * sn[1] + a3 * cs[1];
          float b0 = v1[0], b1 = v1[1], b2 = v1[2], b3 = v1[3];
          v1[0] = b0 * cs[2] - b1 * sn[2];
          v1[1] = b0 * sn[2] + b1 * cs[2];
          v1[2] = b2 * cs[3] - b3 * sn[3];
          v1[3] = b2 * sn[3] + b3 * cs[3];
        }
        u16x8 o;
#pragma unroll
        for (int j = 0; j < 4; j++) { o[j] = f2bf(v0[j]); o[j + 4] = f2bf(v1[j]); }
        *(u16x8*)&((unsigned short*)Cout)[(size_t)grow * N + col0 + c] = o;
      }
    } else {  // EPI == 1: fp32 out = res + gate*acc
#pragma unroll
      for (int c = tc; c < 128; c += 64) {
        int gc = col0 + c;
        f32x4 v0 = *(const f32x4*)&eps[tr][c];
        f32x4 v1 = *(const f32x4*)&eps[tr][c + 4];
        const float* rp = res + (size_t)grow * N + gc;
        f32x4 r0 = *(const f32x4*)rp;
        f32x4 r1 = *(const f32x4*)(rp + 4);
        f32x4 g0 = (f32x4)(1.0f), g1 = (f32x4)(1.0f);
        if (gate) {
          const float* gp = gate + (grow >> 11) * 6144 + gc;
          g0 = *(const f32x4*)gp;
          g1 = *(const f32x4*)(gp + 4);
        }
        f32x4 o0, o1;
#pragma unroll
        for (int j = 0; j < 4; j++) {
          o0[j] = r0[j] + g0[j] * v0[j];
          o1[j] = r1[j] + g1[j] * v1[j];
        }
        float* op = (float*)Cout + (size_t)grow * N + gc;
        *(f32x4*)op = o0;
        *(f32x4*)(op + 4) = o1;
      }
    }
  }
#undef STAGEP
}

// ---------- 256x128-tile pipelined GEMM + fused swiglu (MLP gate/up) ----------
// 3 LDS slots x 24KB = 72KB -> 2 blocks/CU. Verified round 7 (81 us).
#define GX_NT 32  // K/32

__global__ __launch_bounds__(512, 2) void gemm256_swiglu(
    const unsigned short* __restrict__ A, const unsigned short* __restrict__ Bt,
    unsigned short* __restrict__ out) {
  __shared__ char smem[73728];  // 3 slots x 24576
  int tid = threadIdx.x;
  int wave = tid >> 6, lane = tid & 63;
  int wm2 = wave >> 2, wn4 = wave & 3;
  int nwg = gridDim.x;  // 1024
  int bid = blockIdx.x;
  int swz = (bid & 7) * (nwg >> 3) + (bid >> 3);
  int bm = swz & 15, bn = swz >> 4;  // M-fastest within XCD chunk -> B-panel L2 reuse
  int row0 = bm * 256;

  const unsigned short* aB =
      A + (size_t)(row0 + wave * 16 + (lane >> 2)) * 1024 + (lane & 3) * 8;
  const unsigned short* bB =
      Bt + (size_t)(bn * 128 + wave * 16 + (lane >> 2)) * 1024 + (lane & 3) * 8;

#define STAGEX(kt, si)                                              \
  {                                                                 \
    char* dA = smem + (si) * 24576 + wave * 1024;                   \
    char* dB = smem + (si) * 24576 + 16384 + wave * 1024;           \
    const unsigned short* sa_ = aB + (kt) * 32;                     \
    const unsigned short* sb_ = bB + (kt) * 32;                     \
    ldsload16(sa_, dA);                                             \
    ldsload16(sa_ + (size_t)128 * 1024, dA + 8192);                 \
    ldsload16(sb_, dB);                                             \
  }

  f32x4 acc[8][2];
#pragma unroll
  for (int mi = 0; mi < 8; mi++)
#pragma unroll
    for (int ni = 0; ni < 2; ni++) acc[mi][ni] = (f32x4)(0.0f);

  STAGEX(0, 0);
  STAGEX(1, 1);

  int l15 = lane & 15, lk = (lane >> 4) * 8;
  int slot = 0;
  for (int t = 0; t < GX_NT; t++) {
    asm volatile("s_waitcnt vmcnt(3) lgkmcnt(0)\n\ts_barrier" ::: "memory");
    int kt2 = t + 2;
    if (kt2 >= GX_NT) kt2 -= GX_NT;  // tail: dummy restage (unread), uniform count
    int s2 = slot + 2;
    if (s2 >= 3) s2 -= 3;
    STAGEX(kt2, s2);
    const unsigned short* As = (const unsigned short*)(smem + slot * 24576);
    const unsigned short* Bs = (const unsigned short*)(smem + slot * 24576 + 16384);
    bf16x8 bfr[2], af[8];
#pragma unroll
    for (int ni = 0; ni < 2; ni++)
      bfr[ni] = *(const bf16x8*)&Bs[(wn4 * 32 + ni * 16 + l15) * 32 + lk];
#pragma unroll
    for (int mi = 0; mi < 8; mi++)
      af[mi] = *(const bf16x8*)&As[(wm2 * 128 + mi * 16 + l15) * 32 + lk];
    __builtin_amdgcn_s_setprio(1);
#pragma unroll
    for (int mi = 0; mi < 8; mi++)
#pragma unroll
      for (int ni = 0; ni < 2; ni++)
        acc[mi][ni] =
            __builtin_amdgcn_mfma_f32_16x16x32_bf16(af[mi], bfr[ni], acc[mi][ni], 0, 0, 0);
    __builtin_amdgcn_s_setprio(0);
    slot++;
    if (slot == 3) slot = 0;
  }
  // drain dummy loads before reusing LDS as epilogue buffer
  asm volatile("s_waitcnt vmcnt(0) lgkmcnt(0)\n\ts_barrier" ::: "memory");

  // epilogue: 4 passes of 64 rows
  float(*eps)[132] = (float(*)[132])smem;  // [64][132]
  int tr = tid >> 3, tc8 = (tid & 7) * 8;
#pragma unroll
  for (int p = 0; p < 4; p++) {
    __syncthreads();
#pragma unroll
    for (int q = 0; q < 2; q++) {
      int mi = p * 2 + q;
#pragma unroll
      for (int ni = 0; ni < 2; ni++)
#pragma unroll
        for (int r = 0; r < 4; r++)
          eps[wm2 * 32 + q * 16 + (lane >> 4) * 4 + r][wn4 * 32 + ni * 16 + l15] =
              acc[mi][ni][r];
    }
    __syncthreads();
    f32x4 g0 = *(const f32x4*)&eps[tr][tc8];
    f32x4 g1 = *(const f32x4*)&eps[tr][tc8 + 4];
    f32x4 u0 = *(const f32x4*)&eps[tr][64 + tc8];
    f32x4 u1 = *(const f32x4*)&eps[tr][64 + tc8 + 4];
    u16x8 o;
#pragma unroll
    for (int jj = 0; jj < 4; jj++) {
      float a = g0[jj], b2 = g1[jj];
      float ea = __builtin_amdgcn_exp2f(-a * LOG2E);
      float eb = __builtin_amdgcn_exp2f(-b2 * LOG2E);
      o[jj] = f2bf(a * __builtin_amdgcn_rcpf(1.0f + ea) * u0[jj]);
      o[jj + 4] = f2bf(b2 * __builtin_amdgcn_rcpf(1.0f + eb) * u1[jj]);
    }
    int grow = row0 + (tr >> 5) * 128 + p * 32 + (tr & 31);
    *(u16x8*)&out[(size_t)grow * 4096 + bn * 64 + tc8] = o;
  }
#undef STAGEX
}

// ---------- V transpose: in bf16 [b][l][..h..][d] -> out bf16 [b*H+h][d][l] ----------
__global__ __launch_bounds__(256) void vtrans(const unsigned short* __restrict__ in,
                                              unsigned short* __restrict__ out,
                                              int lstride, size_t bstride, int Lk) {
  int lt = blockIdx.x, h = blockIdx.y, b = blockIdx.z;
  __shared__ unsigned short tile[64][72];
  int t = threadIdx.x;
  int lrow = t >> 2, dp = (t & 3) * 16;
  const unsigned short* src =
      in + (size_t)b * bstride + (size_t)(lt * 64 + lrow) * lstride + h * 64 + dp;
  u32x4 v0 = *(const u32x4*)src;
  u32x4 v1 = *(const u32x4*)(src + 8);
  *(u32x4*)&tile[lrow][dp] = v0;
  *(u32x4*)&tile[lrow][dp + 8] = v1;
  __syncthreads();
  int d = t >> 2, lp = (t & 3) * 16;
  u16x8 t0, t1;
#pragma unroll
  for (int i = 0; i < 8; i++) {
    t0[i] = tile[lp + i][d];
    t1[i] = tile[lp + 8 + i][d];
  }
  unsigned short* dst = out + ((size_t)(b * 16 + h) * 64 + d) * Lk + lt * 64 + lp;
  *(u16x8*)dst = t0;
  *(u16x8*)(dst + 8) = t1;
}

// ---------- flash attention v6: pipelined QK(t+1) || softmax(t) ----------
// K double-buffered in LDS (Ks[2]); V single-buffered, written only after the
// post-PV barrier. Raw barriers with lgkmcnt(0) ONLY (no vmcnt drain) so the
// 2-tile register prefetch of K/V stays in flight across barriers.
// Per tile: write K(t+1) -> bar1 -> QK^T(t+1) [MFMA, consumed next iter]
// interleaved with softmax(t) [VALU] -> PV(t) -> bar2 -> write V(t+1).
// Race audit: Ks write/read split by bar1; Vs writes after bar2 (all PV reads
// drained via each wave's lgkmcnt(0)), reads after next bar1. V regs ping-pong
// (vrg[2]) so t+2 loads never clobber the pending t+1 write.
// LDS ~39.4KB -> 4 blocks/CU. Defer-max (THR=8) kept.
__global__ __launch_bounds__(256, 4) void attn6(const unsigned short* __restrict__ qb, int q_ls,
                                                size_t q_bs,
                                                const unsigned short* __restrict__ kb, int k_ls,
                                                size_t k_bs,
                                                const unsigned short* __restrict__ vt,
                                                unsigned short* __restrict__ ob, int o_ls,
                                                size_t o_bs, int Lk) {
  int qt = blockIdx.x, h = blockIdx.y, b = blockIdx.z;
  int tid = threadIdx.x;
  int w = tid >> 6, lane = tid & 63;
  int mrow = lane & 15, grp = lane >> 4;
  int q0 = qt * 64 + w * 16;
  __shared__ unsigned short Ks[2][64][72];
  __shared__ unsigned short Vs[80][72];
  __shared__ unsigned short Ps[4][16][72];
  __shared__ float alf[4][16];

  const unsigned short* qp =
      qb + (size_t)b * q_bs + (size_t)(q0 + mrow) * q_ls + h * 64 + grp * 8;
  bf16x8 qf0, qf1;
  {
    F8 f;
    f.u = *(const u32x4*)qp;
    qf0 = f.v;
    f.u = *(const u32x4*)(qp + 32);
    qf1 = f.v;
  }
  const unsigned short* kbb = kb + (size_t)b * k_bs + h * 64;
  const unsigned short* vtb = vt + (size_t)(b * 16 + h) * 64 * Lk;

  // ones rows 64..79 of Vs (row 64 = 1.0 -> l accumulates in o[4])
  if (tid < 128) {
    int r = 64 + (tid >> 3), c = (tid & 7) * 8;
    unsigned short val = (tid >> 3) == 0 ? (unsigned short)0x3F80 : (unsigned short)0;
    u16x8 vv;
#pragma unroll
    for (int j = 0; j < 8; j++) vv[j] = val;
    *(u16x8*)&Vs[r][c] = vv;
  }

  const float K2 = 0.125f * LOG2E;
  float m_run = -INFINITY;
  f32x4 o[5];
#pragma unroll
  for (int n5 = 0; n5 < 5; n5++) o[n5] = (f32x4)(0.0f);

  int srow = tid >> 3, scol = (tid & 7) * 8;
  int nt = Lk >> 6;
  u32x4 kreg[2], vrg[2][2];
  // tile 0 -> LDS directly
  {
    u32x4 k0[2], v0[2];
#pragma unroll
    for (int i = 0; i < 2; i++) {
      k0[i] = *(const u32x4*)(kbb + (size_t)(srow + i * 32) * k_ls + scol);
      v0[i] = *(const u32x4*)(vtb + (size_t)(srow + i * 32) * Lk + scol);
    }
#pragma unroll
    for (int i = 0; i < 2; i++) {
      *(u32x4*)&Ks[0][srow + i * 32][scol] = k0[i];
      *(u32x4*)&Vs[srow + i * 32][scol] = v0[i];
    }
  }
  if (nt > 1) {  // tile 1 -> regs (in flight across the barrier)
#pragma unroll
    for (int i = 0; i < 2; i++) {
      kreg[i] = *(const u32x4*)(kbb + (size_t)(64 + srow + i * 32) * k_ls + scol);
      vrg[1][i] = *(const u32x4*)(vtb + (size_t)(srow + i * 32) * Lk + 64 + scol);
    }
  }
  asm volatile("s_waitcnt lgkmcnt(0)\n\ts_barrier" ::: "memory");

  // QK^T(0) -> scc
  f32x4 scc[4];
#pragma unroll
  for (int si = 0; si < 4; si++) {
    F8 kf0, kf1;
    kf0.u = *(const u32x4*)&Ks[0][si * 16 + mrow][grp * 8];
    kf1.u = *(const u32x4*)&Ks[0][si * 16 + mrow][32 + grp * 8];
    f32x4 s = (f32x4)(0.0f);
    s = __builtin_amdgcn_mfma_f32_16x16x32_bf16(kf0.v, qf0, s, 0, 0, 0);
    s = __builtin_amdgcn_mfma_f32_16x16x32_bf16(kf1.v, qf1, s, 0, 0, 0);
    scc[si] = s;
  }

  for (int t = 0; t < nt; t++) {
    bool tp1 = (t + 1) < nt, tp2 = (t + 2) < nt;
    if (tp1) {
#pragma unroll
      for (int i = 0; i < 2; i++)
        *(u32x4*)&Ks[(t + 1) & 1][srow + i * 32][scol] = kreg[i];
    }
    if (tp2) {
      int kn = (t + 2) * 64;
#pragma unroll
      for (int i = 0; i < 2; i++) {
        kreg[i] = *(const u32x4*)(kbb + (size_t)(kn + srow + i * 32) * k_ls + scol);
        vrg[t & 1][i] = *(const u32x4*)(vtb + (size_t)(srow + i * 32) * Lk + kn + scol);
      }
    }
    asm volatile("s_waitcnt lgkmcnt(0)\n\ts_barrier" ::: "memory");  // bar1

    // QK^T(t+1): MFMA stream, results unused until next iter (no wait)
    f32x4 scn[4];
    if (tp1) {
#pragma unroll
      for (int si = 0; si < 4; si++) {
        F8 kf0, kf1;
        kf0.u = *(const u32x4*)&Ks[(t + 1) & 1][si * 16 + mrow][grp * 8];
        kf1.u = *(const u32x4*)&Ks[(t + 1) & 1][si * 16 + mrow][32 + grp * 8];
        f32x4 s = (f32x4)(0.0f);
        s = __builtin_amdgcn_mfma_f32_16x16x32_bf16(kf0.v, qf0, s, 0, 0, 0);
        s = __builtin_amdgcn_mfma_f32_16x16x32_bf16(kf1.v, qf1, s, 0, 0, 0);
        scn[si] = s;
      }
    }

    // softmax(t) on scc (VALU; overlaps the QK MFMAs above)
    f32x4 mv = scc[0];
#pragma unroll
    for (int si = 1; si < 4; si++) {
#pragma unroll
      for (int r = 0; r < 4; r++) mv[r] = fmaxf(mv[r], scc[si][r]);
    }
    float v = fmaxf(fmaxf(mv[0], mv[1]), fmaxf(mv[2], mv[3])) * K2;
    v = fmaxf(v, __shfl_xor(v, 16, 64));
    v = fmaxf(v, __shfl_xor(v, 32, 64));
    bool renorm = __any(v > m_run + 8.0f);
    if (renorm) {
      float mnew = fmaxf(m_run, v);
      float alpha = __builtin_amdgcn_exp2f(m_run - mnew);
      m_run = mnew;
      if (lane < 16) alf[w][lane] = alpha;
    }
    float negm = -m_run;
#pragma unroll
    for (int si = 0; si < 4; si++) {
      float p0 = __builtin_amdgcn_exp2f(fmaf(scc[si][0], K2, negm));
      float p1 = __builtin_amdgcn_exp2f(fmaf(scc[si][1], K2, negm));
      float p2 = __builtin_amdgcn_exp2f(fmaf(scc[si][2], K2, negm));
      float p3 = __builtin_amdgcn_exp2f(fmaf(scc[si][3], K2, negm));
      u32x2 pk;
      pk[0] = (__float_as_uint(p0) >> 16) | (__float_as_uint(p1) & 0xFFFF0000u);
      pk[1] = (__float_as_uint(p2) >> 16) | (__float_as_uint(p3) & 0xFFFF0000u);
      *(u32x2*)&Ps[w][mrow][si * 16 + grp * 4] = pk;
    }
    if (renorm) {
      f32x4 av = *(const f32x4*)&alf[w][grp * 4];
#pragma unroll
      for (int n5 = 0; n5 < 5; n5++) {
#pragma unroll
        for (int r = 0; r < 4; r++) o[n5][r] *= av[r];
      }
    }
    bf16x8 pf[2];
#pragma unroll
    for (int kk = 0; kk < 2; kk++) {
      F8 f;
      f.u = *(const u32x4*)&Ps[w][mrow][kk * 32 + grp * 8];
      pf[kk] = f.v;
    }
    // PV(t)
#pragma unroll
    for (int n5 = 0; n5 < 5; n5++) {
#pragma unroll
      for (int kk = 0; kk < 2; kk++) {
        F8 vf;
        vf.u = *(const u32x4*)&Vs[n5 * 16 + mrow][kk * 32 + grp * 8];
        o[n5] = __builtin_amdgcn_mfma_f32_16x16x32_bf16(pf[kk], vf.v, o[n5], 0, 0, 0);
      }
    }
    asm volatile("s_waitcnt lgkmcnt(0)\n\ts_barrier" ::: "memory");  // bar2
    if (tp1) {
#pragma unroll
      for (int i = 0; i < 2; i++)
        *(u32x4*)&Vs[srow + i * 32][scol] = vrg[(t + 1) & 1][i];
#pragma unroll
      for (int si = 0; si < 4; si++) scc[si] = scn[si];
    }
  }
  float inv[4];
#pragma unroll
  for (int r = 0; r < 4; r++) {
    float lv = __shfl(o[4][r], lane & 48, 64);
    inv[r] = 1.0f / lv;
  }
  unsigned short* op = ob + (size_t)b * o_bs + h * 64;
#pragma unroll
  for (int n5 = 0; n5 < 4; n5++)
#pragma unroll
    for (int r = 0; r < 4; r++) {
      int row = q0 + grp * 4 + r;
      op[(size_t)row * o_ls + n5 * 16 + mrow] = f2bf(o[n5][r] * inv[r]);
    }
}

// ---------- launcher ----------
extern "C" void kernel_launch(void* const* d_in, const int* in_sizes, int n_in, void* d_out,
                              int out_size, void* d_ws, size_t ws_size, hipStream_t stream) {
  const float* x = (const float*)d_in[0];
  const float* t_mod = (const float*)d_in[1];
  const float* audio = (const float*)d_in[2];
  const float* fcos = (const float*)d_in[3];
  const float* fsin = (const float*)d_in[4];
  const float* norm1_w = (const float*)d_in[5];
  const float* norm2_w = (const float*)d_in[6];
  const float* norm3_w = (const float*)d_in[7];
  const float* W_qkv = (const float*)d_in[8];
  const float* W_sa = (const float*)d_in[9];
  const float* W_q = (const float*)d_in[10];
  const float* W_kv = (const float*)d_in[11];
  const float* W_ca = (const float*)d_in[12];
  const float* W_gate = (const float*)d_in[13];
  const float* W_up = (const float*)d_in[14];
  const float* W_down = (const float*)d_in[15];
  const float* adaW = (const float*)d_in[16];
  const float* adaB = (const float*)d_in[17];

  char* ws = (char*)d_ws;
  float* x_res = (float*)d_out;  // residual stream lives in d_out (fp32)

  unsigned short* wt_qkv = (unsigned short*)(ws + 0);
  unsigned short* wt_sa = (unsigned short*)(ws + 6291456);
  unsigned short* wt_q = (unsigned short*)(ws + 8388608);
  unsigned short* wt_kv = (unsigned short*)(ws + 10485760);
  unsigned short* wt_ca = (unsigned short*)(ws + 13631488);
  unsigned short* wt_gu = (unsigned short*)(ws + 15728640);  // 8192x1024, 64-blk interleave
  unsigned short* wt_down = (unsigned short*)(ws + 32505856);
  unsigned short* audio_bf = (unsigned short*)(ws + 40894464);
  float* mods = (float*)(ws + 42467328);
  unsigned short* x_sa = (unsigned short*)(ws + 42516480);
  unsigned short* qkv = (unsigned short*)(ws + 50905088);
  unsigned short* vt_s = (unsigned short*)(ws + 76070912);
  unsigned short* sa = (unsigned short*)(ws + 84459520);
  unsigned short* xn = (unsigned short*)(ws + 42516480);
  unsigned short* qc = (unsigned short*)(ws + 50905088);
  unsigned short* kvc = (unsigned short*)(ws + 59293696);
  unsigned short* vt_c = (unsigned short*)(ws + 63488000);
  unsigned short* ca = (unsigned short*)(ws + 65585152);
  unsigned short* x_mlp = (unsigned short*)(ws + 42516480);
  unsigned short* hbuf = (unsigned short*)(ws + 50905088);  // 4096 x 4096 bf16 = 32MB

  // weight prep: one launch for all transposes
  WTArgs wa;
  wa.d[0] = {W_qkv, wt_qkv, 1024, 3072, 0, 0, 96 * 32};
  wa.d[1] = {W_sa, wt_sa, 1024, 1024, 0, 0, 32 * 32};
  wa.d[2] = {W_q, wt_q, 1024, 1024, 0, 0, 32 * 32};
  wa.d[3] = {W_kv, wt_kv, 768, 2048, 0, 0, 64 * 24};
  wa.d[4] = {W_ca, wt_ca, 1024, 1024, 0, 0, 32 * 32};
  wa.d[5] = {W_gate, wt_gu, 1024, 4096, 6, 0, 128 * 32};
  wa.d[6] = {W_up, wt_gu, 1024, 4096, 6, 64, 128 * 32};
  wa.d[7] = {W_down, wt_down, 4096, 1024, 0, 0, 32 * 128};
  int total_tiles = 3072 + 1024 + 1024 + 1536 + 1024 + 4096 + 4096 + 4096;
  wtrans_all<<<total_tiles, 256, 0, stream>>>(wa);
  f2bf_copy<<<768, 256, 0, stream>>>(audio, audio_bf, 786432);
  mods_kernel<<<dim3(96, 2), 256, 0, stream>>>(t_mod, adaW, adaB, mods);

  // self-attention block
  rmsnorm_mod<<<4096, 256, 0, stream>>>(x, norm1_w, mods, 0, 1024, x_sa);
  gemm_pipe<3, 128><<<dim3(32, 24), 256, 0, stream>>>(x_sa, wt_qkv, qkv, nullptr, nullptr,
                                                      fcos, fsin, 3072, 1024, 1024);
  vtrans<<<dim3(32, 16, 2), 256, 0, stream>>>(qkv + 2048, vt_s, 3072, 6291456, 2048);
  attn6<<<dim3(32, 16, 2), 256, 0, stream>>>(qkv, 3072, 6291456, qkv + 1024, 3072, 6291456,
                                             vt_s, sa, 1024, 2097152, 2048);
  gemm_pipe<1, 64><<<dim3(64, 8), 256, 0, stream>>>(sa, wt_sa, x_res, x, mods + 2048, nullptr,
                                                    nullptr, 1024, 1024, 1024);

  // cross-attention block
  rmsnorm_mod<<<4096, 256, 0, stream>>>(x_res, norm2_w, nullptr, 0, 0, xn);
  gemm_pipe<0, 64><<<dim3(64, 8), 256, 0, stream>>>(xn, wt_q, qc, nullptr, nullptr, nullptr,
                                                    nullptr, 1024, 1024, 1024);
  gemm_pipe<0, 64><<<dim3(16, 16), 256, 0, stream>>>(audio_bf, wt_kv, kvc, nullptr, nullptr,
                                                     nullptr, nullptr, 2048, 768, 768);
  vtrans<<<dim3(8, 16, 2), 256, 0, stream>>>(kvc + 1024, vt_c, 2048, 1048576, 512);
  attn6<<<dim3(32, 16, 2), 256, 0, stream>>>(qc, 1024, 2097152, kvc, 2048, 1048576, vt_c, ca,
                                             1024, 2097152, 512);
  gemm_pipe<1, 64><<<dim3(64, 8), 256, 0, stream>>>(ca, wt_ca, x_res, x_res, nullptr, nullptr,
                                                    nullptr, 1024, 1024, 1024);

  // MLP block: 256x128 pipelined gate+up with fused swiglu -> hbuf, then pipelined down
  rmsnorm_mod<<<4096, 256, 0, stream>>>(x_res, norm3_w, mods, 3072, 4096, x_mlp);
  gemm256_swiglu<<<1024, 512, 0, stream>>>(x_mlp, wt_gu, hbuf);
  gemm_pipe<1, 64><<<dim3(64, 8), 256, 0, stream>>>(hbuf, wt_down, x_res, x_res, mods + 5120,
                                                    nullptr, nullptr, 1024, 4096, 4096);
}

// Round 9
// 552.740 us; speedup vs baseline: 1.0493x; 1.0493x over previous
//
#include <hip/hip_runtime.h>
#include <math.h>

// ---------- types ----------
typedef __attribute__((ext_vector_type(4))) float f32x4;
typedef __attribute__((ext_vector_type(16))) float f32x16;
typedef __attribute__((ext_vector_type(4))) unsigned int u32x4;
typedef __attribute__((ext_vector_type(2))) unsigned int u32x2;
typedef __attribute__((ext_vector_type(8))) unsigned short u16x8;
typedef __attribute__((ext_vector_type(4))) unsigned short u16x4;
typedef __attribute__((ext_vector_type(8))) __bf16 bf16x8;

union F8 { u32x4 u; u16x8 us; bf16x8 v; };

#define LOG2E 1.4426950408889634f

__device__ __forceinline__ unsigned short f2bf(float f) {
  unsigned int u = __float_as_uint(f);
  u += 0x7fffu + ((u >> 16) & 1u);
  return (unsigned short)(u >> 16);
}
__device__ __forceinline__ float bf2f(unsigned short s) {
  return __uint_as_float(((unsigned int)s) << 16);
}

// async global->LDS, 16B per lane; lds dest = wave-uniform base + lane*16
__device__ __forceinline__ void ldsload16(const void* g, void* l) {
  __builtin_amdgcn_global_load_lds((const __attribute__((address_space(1))) unsigned int*)g,
                                   (__attribute__((address_space(3))) unsigned int*)l, 16, 0, 0);
}

// ---------- all weight transposes in one launch ----------
// in fp32 (K x N) -> out bf16 (row' x K); remap=s>0: row' = ((n>>s)<<(s+1))+(n&((1<<s)-1))+radd
struct WTDesc {
  const float* in;
  unsigned short* out;
  int K, N, remap, radd, tiles;
};
struct WTArgs { WTDesc d[8]; };

__global__ __launch_bounds__(256) void wtrans_all(WTArgs a) {
  __shared__ float tile[32][33];
  int t = blockIdx.x, i = 0;
  while (t >= a.d[i].tiles) { t -= a.d[i].tiles; i++; }
  const float* in = a.d[i].in;
  unsigned short* out = a.d[i].out;
  int K = a.d[i].K, N = a.d[i].N, remap = a.d[i].remap, radd = a.d[i].radd;
  int ntx = N >> 5;
  int n0 = (t % ntx) * 32, k0 = (t / ntx) * 32;
  int tx = threadIdx.x & 31, ty = threadIdx.x >> 5;
#pragma unroll
  for (int s = 0; s < 32; s += 8)
    tile[ty + s][tx] = in[(size_t)(k0 + ty + s) * N + n0 + tx];
  __syncthreads();
#pragma unroll
  for (int s = 0; s < 32; s += 8) {
    int n = n0 + ty + s;
    int rowp = remap ? (((n >> remap) << (remap + 1)) + (n & ((1 << remap) - 1)) + radd) : n;
    out[(size_t)rowp * K + k0 + tx] = f2bf(tile[tx][ty + s]);
  }
}

// ---------- flat fp32 -> bf16 ----------
__global__ __launch_bounds__(256) void f2bf_copy(const float* __restrict__ in,
                                                 unsigned short* __restrict__ out, int n) {
  int i = (blockIdx.x * 256 + threadIdx.x) * 4;
  if (i < n) {
    f32x4 v = *(const f32x4*)(in + i);
    u16x4 o;
#pragma unroll
    for (int j = 0; j < 4; j++) o[j] = f2bf(v[j]);
    *(u16x4*)(out + i) = o;
  }
}

// ---------- mods = silu(t_mod) @ adaLN_W + adaLN_b ; (B x 6144) fp32 ----------
// split-k: block covers 64 cols x 4 k-groups of 256; grid (96, 2) = 192 blocks.
__global__ __launch_bounds__(256) void mods_kernel(const float* __restrict__ t_mod,
                                                   const float* __restrict__ W,
                                                   const float* __restrict__ bias,
                                                   float* __restrict__ mods) {
  int b = blockIdx.y;
  int tid = threadIdx.x;
  int j = blockIdx.x * 64 + (tid & 63);
  int kg = tid >> 6;
  __shared__ float a_s[1024];
  __shared__ float red[4][64];
  for (int i = tid; i < 1024; i += 256) {
    float tv = t_mod[b * 1024 + i];
    a_s[i] = tv / (1.0f + expf(-tv));
  }
  __syncthreads();
  float acc = 0.0f;
  int k0 = kg * 256;
  for (int k = k0; k < k0 + 256; k++) acc = fmaf(a_s[k], W[(size_t)k * 6144 + j], acc);
  red[kg][tid & 63] = acc;
  __syncthreads();
  if (kg == 0) {
    float s = red[0][tid] + red[1][tid] + red[2][tid] + red[3][tid] + bias[j];
    mods[b * 6144 + j] = s;
  }
}

// ---------- rmsnorm (+ optional adaLN modulation), fp32 in -> bf16 out ----------
__global__ __launch_bounds__(256) void rmsnorm_mod(const float* __restrict__ x,
                                                   const float* __restrict__ w,
                                                   const float* mods, int shift_off,
                                                   int scale_off,
                                                   unsigned short* __restrict__ out) {
  int row = blockIdx.x;
  int b = row >> 11;
  const float* xr = x + (size_t)row * 1024;
  int t = threadIdx.x;
  f32x4 xv = *(const f32x4*)(xr + t * 4);
  float ss = xv[0] * xv[0] + xv[1] * xv[1] + xv[2] * xv[2] + xv[3] * xv[3];
#pragma unroll
  for (int off = 32; off >= 1; off >>= 1) ss += __shfl_xor(ss, off, 64);
  __shared__ float red[4];
  if ((t & 63) == 0) red[t >> 6] = ss;
  __syncthreads();
  float tot = red[0] + red[1] + red[2] + red[3];
  float rr = rsqrtf(tot * (1.0f / 1024.0f) + 1e-6f);
  f32x4 wv = *(const f32x4*)(w + t * 4);
  f32x4 scv = (f32x4)(0.0f), shv = (f32x4)(0.0f);
  if (mods) {
    scv = *(const f32x4*)(mods + b * 6144 + scale_off + t * 4);
    shv = *(const f32x4*)(mods + b * 6144 + shift_off + t * 4);
  }
  u16x4 ov;
#pragma unroll
  for (int j = 0; j < 4; j++) {
    float n = xv[j] * rr * wv[j];
    ov[j] = f2bf(n * (1.0f + scv[j]) + shv[j]);
  }
  *(u16x4*)(out + (size_t)row * 1024 + t * 4) = ov;
}

// ---------- pipelined GEMM: C = A(MxK,bf16,lda) * Bt(NxK,bf16)^T ----------
// TM in {128, 64}. 4 LDS bufs, 3-tile lookahead, counted vmcnt, lgkmcnt(0)
// folded pre-barrier. Chunk swizzle c ^= (row>>1)&3 BOTH sides (global source
// pre-swizzled for global_load_lds; same involution on frag reads): each
// 16-lane ds_read_b128 phase puts exactly 2 rows per 4-bank slot -> 2-way = free.
// (Old r&3 XOR double-counted the parity bit -> residual 4-way.)
// EPI 0: bf16 store. EPI 1: fp32 out = res + gate*acc. EPI 3: bf16 + RoPE cols<2048.
template <int EPI, int TM>
__global__ __launch_bounds__(256) void gemm_pipe(const unsigned short* __restrict__ A,
                                                 const unsigned short* __restrict__ Bt,
                                                 void* Cout, const float* res,
                                                 const float* gate, const float* fcos,
                                                 const float* fsin, int N, int K, int lda) {
  constexpr int BUF = TM * 64 + 8192;  // bytes per buffer (A tile + B tile)
  constexpr int TN = (TM == 128) ? 2 : 1;
  __shared__ char smem[4 * BUF];
  int tid = threadIdx.x;
  int wave = tid >> 6, lane = tid & 63;
  int row0 = blockIdx.x * TM, col0 = blockIdx.y * 128;
  int wm = (TM == 128) ? (wave & 1) * 64 : 0;
  int wn = (TM == 128) ? (wave >> 1) * 64 : wave * 32;
  int ln31 = lane & 31, lk5 = lane >> 5;
  int cxor = (ln31 >> 1) & 3;  // s(row) for frag rows (row mod 32 = ln31)
  int co[2];
#pragma unroll
  for (int ks = 0; ks < 2; ks++) co[ks] = ((lk5 + 2 * ks) ^ cxor) * 8;

  // staging: thread slot = LDS row srow, chunk (tid&3); source chunk XOR'd by
  // s(srow) = (srow>>1)&3 = (tid>>3)&3 so LDS[R][c] = G[R][c ^ s(R)]
  int srow = tid >> 2;
  int schunk = (tid & 3) ^ ((tid >> 3) & 3);
  const unsigned short* aB = A + (size_t)(row0 + srow) * lda + schunk * 8;
  const unsigned short* bB = Bt + (size_t)(col0 + srow) * K + schunk * 8;

#define STAGEP(kt, bi)                                                       \
  {                                                                          \
    char* dA = smem + (bi) * BUF + wave * 1024;                              \
    char* dB = smem + (bi) * BUF + TM * 64 + wave * 1024;                    \
    const unsigned short* sa_ = aB + (kt) * 32;                              \
    const unsigned short* sb_ = bB + (kt) * 32;                              \
    ldsload16(sa_, dA);                                                      \
    if constexpr (TM == 128) ldsload16(sa_ + 64 * (size_t)lda, dA + 4096);   \
    ldsload16(sb_, dB);                                                      \
    ldsload16(sb_ + 64 * (size_t)K, dB + 4096);                              \
  }

  f32x16 acc[2][TN];
#pragma unroll
  for (int i = 0; i < 2; i++)
#pragma unroll
    for (int j = 0; j < TN; j++) acc[i][j] = (f32x16)(0.0f);

  int nk = K >> 5;
  STAGEP(0, 0);
  STAGEP(1, 1);
  STAGEP(2, 2);

  for (int t = 0; t < nk; t++) {
    if constexpr (TM == 128)
      asm volatile("s_waitcnt vmcnt(8) lgkmcnt(0)\n\ts_barrier" ::: "memory");
    else
      asm volatile("s_waitcnt vmcnt(6) lgkmcnt(0)\n\ts_barrier" ::: "memory");
    int kt3 = t + 3;
    if (kt3 >= nk) kt3 -= nk;  // tail: dummy restage (unread), uniform count
    STAGEP(kt3, (t + 3) & 3);
    const unsigned short* As = (const unsigned short*)(smem + (t & 3) * BUF);
    const unsigned short* Bs = (const unsigned short*)(smem + (t & 3) * BUF + TM * 64);
    bf16x8 af[2][2], bfr[TN][2];
#pragma unroll
    for (int ti = 0; ti < 2; ti++)
#pragma unroll
      for (int ks = 0; ks < 2; ks++)
        af[ti][ks] = *(const bf16x8*)&As[(wm + ti * 32 + ln31) * 32 + co[ks]];
#pragma unroll
    for (int tj = 0; tj < TN; tj++)
#pragma unroll
      for (int ks = 0; ks < 2; ks++)
        bfr[tj][ks] = *(const bf16x8*)&Bs[(wn + tj * 32 + ln31) * 32 + co[ks]];
    __builtin_amdgcn_s_setprio(1);
#pragma unroll
    for (int ks = 0; ks < 2; ks++)
#pragma unroll
      for (int ti = 0; ti < 2; ti++)
#pragma unroll
        for (int tj = 0; tj < TN; tj++)
          acc[ti][tj] = __builtin_amdgcn_mfma_f32_32x32x16_bf16(af[ti][ks], bfr[tj][ks],
                                                                acc[ti][tj], 0, 0, 0);
    __builtin_amdgcn_s_setprio(0);
  }
  asm volatile("s_waitcnt vmcnt(0) lgkmcnt(0)\n\ts_barrier" ::: "memory");

  float(*eps)[132] = (float(*)[132])smem;
  int tr = tid >> 3, tc = (tid & 7) * 8;
  constexpr int NPASS = (TM == 128) ? 4 : 2;
#pragma unroll
  for (int p = 0; p < NPASS; p++) {
    __syncthreads();
    if constexpr (TM == 128) {
      if ((wave & 1) == (p >> 1)) {
        int ti = p & 1;
#pragma unroll
        for (int tj = 0; tj < TN; tj++)
#pragma unroll
          for (int rg = 0; rg < 16; rg++) {
            int rl = (rg & 3) + 8 * (rg >> 2) + 4 * (lane >> 5);
            eps[rl][wn + tj * 32 + ln31] = acc[ti][tj][rg];
          }
      }
    } else {
#pragma unroll
      for (int rg = 0; rg < 16; rg++) {
        int rl = (rg & 3) + 8 * (rg >> 2) + 4 * (lane >> 5);
        eps[rl][wn + ln31] = acc[p][0][rg];
      }
    }
    __syncthreads();
    int grow = row0 + p * 32 + tr;
    if (EPI == 0 || EPI == 3) {
      bool rope = (EPI == 3) && (col0 < 2048);
      int l = grow & 2047;
#pragma unroll
      for (int c = tc; c < 128; c += 64) {
        f32x4 v0 = *(const f32x4*)&eps[tr][c];
        f32x4 v1 = *(const f32x4*)&eps[tr][c + 4];
        if (rope) {
          int d2 = ((col0 + c) & 63) >> 1;
          f32x4 cs = *(const f32x4*)(fcos + l * 32 + d2);
          f32x4 sn = *(const f32x4*)(fsin + l * 32 + d2);
          float a0 = v0[0], a1 = v0[1], a2 = v0[2], a3 = v0[3];
          v0[0] = a0 * cs[0] - a1 * sn[0];
          v0[1] = a0 * sn[0] + a1 * cs[0];
          v0[2] = a2 * cs[1] - a3 * sn[1];
          v0[3] = a2 * sn[1] + a3 * cs[1];
          float b0 = v1[0], b1 = v1[1], b2 = v1[2], b3 = v1[3];
          v1[0] = b0 * cs[2] - b1 * sn[2];
          v1[1] = b0 * sn[2] + b1 * cs[2];
          v1[2] = b2 * cs[3] - b3 * sn[3];
          v1[3] = b2 * sn[3] + b3 * cs[3];
        }
        u16x8 o;
#pragma unroll
        for (int j = 0; j < 4; j++) { o[j] = f2bf(v0[j]); o[j + 4] = f2bf(v1[j]); }
        *(u16x8*)&((unsigned short*)Cout)[(size_t)grow * N + col0 + c] = o;
      }
    } else {  // EPI == 1: fp32 out = res + gate*acc
#pragma unroll
      for (int c = tc; c < 128; c += 64) {
        int gc = col0 + c;
        f32x4 v0 = *(const f32x4*)&eps[tr][c];
        f32x4 v1 = *(const f32x4*)&eps[tr][c + 4];
        const float* rp = res + (size_t)grow * N + gc;
        f32x4 r0 = *(const f32x4*)rp;
        f32x4 r1 = *(const f32x4*)(rp + 4);
        f32x4 g0 = (f32x4)(1.0f), g1 = (f32x4)(1.0f);
        if (gate) {
          const float* gp = gate + (grow >> 11) * 6144 + gc;
          g0 = *(const f32x4*)gp;
          g1 = *(const f32x4*)(gp + 4);
        }
        f32x4 o0, o1;
#pragma unroll
        for (int j = 0; j < 4; j++) {
          o0[j] = r0[j] + g0[j] * v0[j];
          o1[j] = r1[j] + g1[j] * v1[j];
        }
        float* op = (float*)Cout + (size_t)grow * N + gc;
        *(f32x4*)op = o0;
        *(f32x4*)(op + 4) = o1;
      }
    }
  }
#undef STAGEP
}

// ---------- 256x128-tile pipelined GEMM + fused swiglu (MLP gate/up) ----------
// 3 LDS slots x 24KB = 72KB -> 2 blocks/CU. Round-7 structure + bank-conflict
// fix: round-7 counters showed SQ_LDS_BANK_CONFLICT=1.1e7 (~22% of cycles) —
// frag reads with 64B rows and per-16-lane-constant chunk were 8-way conflicted.
// Fix: chunk swizzle c ^= (row>>1)&3 both sides (pre-swizzled global source,
// linear LDS; same involution on reads) -> 2 rows per 4-bank slot = free.
#define GX_NT 32  // K/32

__global__ __launch_bounds__(512, 2) void gemm256_swiglu(
    const unsigned short* __restrict__ A, const unsigned short* __restrict__ Bt,
    unsigned short* __restrict__ out) {
  __shared__ char smem[73728];  // 3 slots x 24576
  int tid = threadIdx.x;
  int wave = tid >> 6, lane = tid & 63;
  int wm2 = wave >> 2, wn4 = wave & 3;
  int nwg = gridDim.x;  // 1024
  int bid = blockIdx.x;
  int swz = (bid & 7) * (nwg >> 3) + (bid >> 3);
  int bm = swz & 15, bn = swz >> 4;  // M-fastest within XCD chunk -> B-panel L2 reuse
  int row0 = bm * 256;

  // staging source chunk = (lane&3) ^ s(R), R = wave*16 + (lane>>2) -> s = (lane>>3)&3
  int sch = ((lane & 3) ^ ((lane >> 3) & 3)) * 8;
  const unsigned short* aB =
      A + (size_t)(row0 + wave * 16 + (lane >> 2)) * 1024 + sch;
  const unsigned short* bB =
      Bt + (size_t)(bn * 128 + wave * 16 + (lane >> 2)) * 1024 + sch;

#define STAGEX(kt, si)                                              \
  {                                                                 \
    char* dA = smem + (si) * 24576 + wave * 1024;                   \
    char* dB = smem + (si) * 24576 + 16384 + wave * 1024;           \
    const unsigned short* sa_ = aB + (kt) * 32;                     \
    const unsigned short* sb_ = bB + (kt) * 32;                     \
    ldsload16(sa_, dA);                                             \
    ldsload16(sa_ + (size_t)128 * 1024, dA + 8192);                 \
    ldsload16(sb_, dB);                                             \
  }

  f32x4 acc[8][2];
#pragma unroll
  for (int mi = 0; mi < 8; mi++)
#pragma unroll
    for (int ni = 0; ni < 2; ni++) acc[mi][ni] = (f32x4)(0.0f);

  STAGEX(0, 0);
  STAGEX(1, 1);

  int l15 = lane & 15;
  // read chunk = (lane>>4) ^ s(row); frag rows = base16k + l15 -> s = (l15>>1)&3
  int lks = (((lane >> 4) ^ ((l15 >> 1) & 3)) & 3) * 8;
  int slot = 0;
  for (int t = 0; t < GX_NT; t++) {
    asm volatile("s_waitcnt vmcnt(3) lgkmcnt(0)\n\ts_barrier" ::: "memory");
    int kt2 = t + 2;
    if (kt2 >= GX_NT) kt2 -= GX_NT;  // tail: dummy restage (unread), uniform count
    int s2 = slot + 2;
    if (s2 >= 3) s2 -= 3;
    STAGEX(kt2, s2);
    const unsigned short* As = (const unsigned short*)(smem + slot * 24576);
    const unsigned short* Bs = (const unsigned short*)(smem + slot * 24576 + 16384);
    bf16x8 bfr[2], af[8];
#pragma unroll
    for (int ni = 0; ni < 2; ni++)
      bfr[ni] = *(const bf16x8*)&Bs[(wn4 * 32 + ni * 16 + l15) * 32 + lks];
#pragma unroll
    for (int mi = 0; mi < 8; mi++)
      af[mi] = *(const bf16x8*)&As[(wm2 * 128 + mi * 16 + l15) * 32 + lks];
    __builtin_amdgcn_s_setprio(1);
#pragma unroll
    for (int mi = 0; mi < 8; mi++)
#pragma unroll
      for (int ni = 0; ni < 2; ni++)
        acc[mi][ni] =
            __builtin_amdgcn_mfma_f32_16x16x32_bf16(af[mi], bfr[ni], acc[mi][ni], 0, 0, 0);
    __builtin_amdgcn_s_setprio(0);
    slot++;
    if (slot == 3) slot = 0;
  }
  // drain dummy loads before reusing LDS as epilogue buffer
  asm volatile("s_waitcnt vmcnt(0) lgkmcnt(0)\n\ts_barrier" ::: "memory");

  // epilogue: 4 passes of 64 rows
  float(*eps)[132] = (float(*)[132])smem;  // [64][132]
  int tr = tid >> 3, tc8 = (tid & 7) * 8;
#pragma unroll
  for (int p = 0; p < 4; p++) {
    __syncthreads();
#pragma unroll
    for (int q = 0; q < 2; q++) {
      int mi = p * 2 + q;
#pragma unroll
      for (int ni = 0; ni < 2; ni++)
#pragma unroll
        for (int r = 0; r < 4; r++)
          eps[wm2 * 32 + q * 16 + (lane >> 4) * 4 + r][wn4 * 32 + ni * 16 + l15] =
              acc[mi][ni][r];
    }
    __syncthreads();
    f32x4 g0 = *(const f32x4*)&eps[tr][tc8];
    f32x4 g1 = *(const f32x4*)&eps[tr][tc8 + 4];
    f32x4 u0 = *(const f32x4*)&eps[tr][64 + tc8];
    f32x4 u1 = *(const f32x4*)&eps[tr][64 + tc8 + 4];
    u16x8 o;
#pragma unroll
    for (int jj = 0; jj < 4; jj++) {
      float a = g0[jj], b2 = g1[jj];
      float ea = __builtin_amdgcn_exp2f(-a * LOG2E);
      float eb = __builtin_amdgcn_exp2f(-b2 * LOG2E);
      o[jj] = f2bf(a * __builtin_amdgcn_rcpf(1.0f + ea) * u0[jj]);
      o[jj + 4] = f2bf(b2 * __builtin_amdgcn_rcpf(1.0f + eb) * u1[jj]);
    }
    int grow = row0 + (tr >> 5) * 128 + p * 32 + (tr & 31);
    *(u16x8*)&out[(size_t)grow * 4096 + bn * 64 + tc8] = o;
  }
#undef STAGEX
}

// ---------- V transpose: in bf16 [b][l][..h..][d] -> out bf16 [b*H+h][d][l] ----------
__global__ __launch_bounds__(256) void vtrans(const unsigned short* __restrict__ in,
                                              unsigned short* __restrict__ out,
                                              int lstride, size_t bstride, int Lk) {
  int lt = blockIdx.x, h = blockIdx.y, b = blockIdx.z;
  __shared__ unsigned short tile[64][72];
  int t = threadIdx.x;
  int lrow = t >> 2, dp = (t & 3) * 16;
  const unsigned short* src =
      in + (size_t)b * bstride + (size_t)(lt * 64 + lrow) * lstride + h * 64 + dp;
  u32x4 v0 = *(const u32x4*)src;
  u32x4 v1 = *(const u32x4*)(src + 8);
  *(u32x4*)&tile[lrow][dp] = v0;
  *(u32x4*)&tile[lrow][dp + 8] = v1;
  __syncthreads();
  int d = t >> 2, lp = (t & 3) * 16;
  u16x8 t0, t1;
#pragma unroll
  for (int i = 0; i < 8; i++) {
    t0[i] = tile[lp + i][d];
    t1[i] = tile[lp + 8 + i][d];
  }
  unsigned short* dst = out + ((size_t)(b * 16 + h) * 64 + d) * Lk + lt * 64 + lp;
  *(u16x8*)dst = t0;
  *(u16x8*)(dst + 8) = t1;
}

// ---------- flash attention v4: 64-key tiles (5 blocks/CU) + defer-max ----------
// S^T softmax, ones-column l trick. Defer-max (THR=8): skip the O-rescale and
// alpha path when no q-row's tile-max exceeds m_run+8 (wave-uniform branch).
// (Reverted from attn5/attn6 pipelining experiments — both regressed; implicit
// wave-level overlap at 4-5 blocks/CU already captures the pipeline gain.)
__global__ __launch_bounds__(256, 5) void attn4(const unsigned short* __restrict__ qb, int q_ls,
                                                size_t q_bs,
                                                const unsigned short* __restrict__ kb, int k_ls,
                                                size_t k_bs,
                                                const unsigned short* __restrict__ vt,
                                                unsigned short* __restrict__ ob, int o_ls,
                                                size_t o_bs, int Lk) {
  int qt = blockIdx.x, h = blockIdx.y, b = blockIdx.z;
  int tid = threadIdx.x;
  int w = tid >> 6, lane = tid & 63;
  int mrow = lane & 15, grp = lane >> 4;
  int q0 = qt * 64 + w * 16;
  __shared__ unsigned short Ks[64][72];
  __shared__ unsigned short Vs[80][72];
  __shared__ unsigned short Ps[4][16][72];
  __shared__ float alf[4][16];

  const unsigned short* qp =
      qb + (size_t)b * q_bs + (size_t)(q0 + mrow) * q_ls + h * 64 + grp * 8;
  bf16x8 qf0, qf1;
  {
    F8 f;
    f.u = *(const u32x4*)qp;
    qf0 = f.v;
    f.u = *(const u32x4*)(qp + 32);
    qf1 = f.v;
  }
  const unsigned short* kbb = kb + (size_t)b * k_bs + h * 64;
  const unsigned short* vtb = vt + (size_t)(b * 16 + h) * 64 * Lk;

  // ones rows 64..79 of Vs (row 64 = 1.0 -> l accumulates in o[4])
  if (tid < 128) {
    int r = 64 + (tid >> 3), c = (tid & 7) * 8;
    unsigned short val = (tid >> 3) == 0 ? (unsigned short)0x3F80 : (unsigned short)0;
    u16x8 vv;
#pragma unroll
    for (int j = 0; j < 8; j++) vv[j] = val;
    *(u16x8*)&Vs[r][c] = vv;
  }

  const float K2 = 0.125f * LOG2E;
  float m_run = -INFINITY;
  f32x4 o[5];
#pragma unroll
  for (int nt = 0; nt < 5; nt++) o[nt] = (f32x4)(0.0f);

  int srow = tid >> 3, scol = (tid & 7) * 8;
  u32x4 kreg[2], vreg[2];
#pragma unroll
  for (int i = 0; i < 2; i++) {
    kreg[i] = *(const u32x4*)(kbb + (size_t)(srow + i * 32) * k_ls + scol);
    vreg[i] = *(const u32x4*)(vtb + (size_t)(srow + i * 32) * Lk + scol);
  }

  for (int k0 = 0; k0 < Lk; k0 += 64) {
    __syncthreads();
#pragma unroll
    for (int i = 0; i < 2; i++) {
      *(u32x4*)&Ks[srow + i * 32][scol] = kreg[i];
      *(u32x4*)&Vs[srow + i * 32][scol] = vreg[i];
    }
    __syncthreads();
    int kn = k0 + 64;
    if (kn < Lk) {
#pragma unroll
      for (int i = 0; i < 2; i++) {
        kreg[i] = *(const u32x4*)(kbb + (size_t)(kn + srow + i * 32) * k_ls + scol);
        vreg[i] = *(const u32x4*)(vtb + (size_t)(srow + i * 32) * Lk + kn + scol);
      }
    }
    f32x4 sc[4];
#pragma unroll
    for (int si = 0; si < 4; si++) {
      F8 kf0, kf1;
      kf0.u = *(const u32x4*)&Ks[si * 16 + mrow][grp * 8];
      kf1.u = *(const u32x4*)&Ks[si * 16 + mrow][32 + grp * 8];
      f32x4 s = (f32x4)(0.0f);
      s = __builtin_amdgcn_mfma_f32_16x16x32_bf16(kf0.v, qf0, s, 0, 0, 0);
      s = __builtin_amdgcn_mfma_f32_16x16x32_bf16(kf1.v, qf1, s, 0, 0, 0);
      sc[si] = s;
    }
    f32x4 mv = sc[0];
#pragma unroll
    for (int si = 1; si < 4; si++) {
#pragma unroll
      for (int r = 0; r < 4; r++) mv[r] = fmaxf(mv[r], sc[si][r]);
    }
    float v = fmaxf(fmaxf(mv[0], mv[1]), fmaxf(mv[2], mv[3])) * K2;
    v = fmaxf(v, __shfl_xor(v, 16, 64));
    v = fmaxf(v, __shfl_xor(v, 32, 64));
    // defer-max: only renormalize when some q-row grew past m_run + 8
    bool renorm = __any(v > m_run + 8.0f);
    if (renorm) {
      float mnew = fmaxf(m_run, v);
      float alpha = __builtin_amdgcn_exp2f(m_run - mnew);
      m_run = mnew;
      if (lane < 16) alf[w][lane] = alpha;
    }
    float negm = -m_run;
#pragma unroll
    for (int si = 0; si < 4; si++) {
      float p0 = __builtin_amdgcn_exp2f(fmaf(sc[si][0], K2, negm));
      float p1 = __builtin_amdgcn_exp2f(fmaf(sc[si][1], K2, negm));
      float p2 = __builtin_amdgcn_exp2f(fmaf(sc[si][2], K2, negm));
      float p3 = __builtin_amdgcn_exp2f(fmaf(sc[si][3], K2, negm));
      u32x2 pk;
      pk[0] = (__float_as_uint(p0) >> 16) | (__float_as_uint(p1) & 0xFFFF0000u);
      pk[1] = (__float_as_uint(p2) >> 16) | (__float_as_uint(p3) & 0xFFFF0000u);
      *(u32x2*)&Ps[w][mrow][si * 16 + grp * 4] = pk;
    }
    if (renorm) {
      f32x4 av = *(const f32x4*)&alf[w][grp * 4];
#pragma unroll
      for (int nt = 0; nt < 5; nt++) {
#pragma unroll
        for (int r = 0; r < 4; r++) o[nt][r] *= av[r];
      }
    }
    bf16x8 pf[2];
#pragma unroll
    for (int kk = 0; kk < 2; kk++) {
      F8 f;
      f.u = *(const u32x4*)&Ps[w][mrow][kk * 32 + grp * 8];
      pf[kk] = f.v;
    }
#pragma unroll
    for (int nt = 0; nt < 5; nt++) {
#pragma unroll
      for (int kk = 0; kk < 2; kk++) {
        F8 vf;
        vf.u = *(const u32x4*)&Vs[nt * 16 + mrow][kk * 32 + grp * 8];
        o[nt] = __builtin_amdgcn_mfma_f32_16x16x32_bf16(pf[kk], vf.v, o[nt], 0, 0, 0);
      }
    }
  }
  float inv[4];
#pragma unroll
  for (int r = 0; r < 4; r++) {
    float lv = __shfl(o[4][r], lane & 48, 64);
    inv[r] = 1.0f / lv;
  }
  unsigned short* op = ob + (size_t)b * o_bs + h * 64;
#pragma unroll
  for (int nt = 0; nt < 4; nt++)
#pragma unroll
    for (int r = 0; r < 4; r++) {
      int row = q0 + grp * 4 + r;
      op[(size_t)row * o_ls + nt * 16 + mrow] = f2bf(o[nt][r] * inv[r]);
    }
}

// ---------- launcher ----------
extern "C" void kernel_launch(void* const* d_in, const int* in_sizes, int n_in, void* d_out,
                              int out_size, void* d_ws, size_t ws_size, hipStream_t stream) {
  const float* x = (const float*)d_in[0];
  const float* t_mod = (const float*)d_in[1];
  const float* audio = (const float*)d_in[2];
  const float* fcos = (const float*)d_in[3];
  const float* fsin = (const float*)d_in[4];
  const float* norm1_w = (const float*)d_in[5];
  const float* norm2_w = (const float*)d_in[6];
  const float* norm3_w = (const float*)d_in[7];
  const float* W_qkv = (const float*)d_in[8];
  const float* W_sa = (const float*)d_in[9];
  const float* W_q = (const float*)d_in[10];
  const float* W_kv = (const float*)d_in[11];
  const float* W_ca = (const float*)d_in[12];
  const float* W_gate = (const float*)d_in[13];
  const float* W_up = (const float*)d_in[14];
  const float* W_down = (const float*)d_in[15];
  const float* adaW = (const float*)d_in[16];
  const float* adaB = (const float*)d_in[17];

  char* ws = (char*)d_ws;
  float* x_res = (float*)d_out;  // residual stream lives in d_out (fp32)

  unsigned short* wt_qkv = (unsigned short*)(ws + 0);
  unsigned short* wt_sa = (unsigned short*)(ws + 6291456);
  unsigned short* wt_q = (unsigned short*)(ws + 8388608);
  unsigned short* wt_kv = (unsigned short*)(ws + 10485760);
  unsigned short* wt_ca = (unsigned short*)(ws + 13631488);
  unsigned short* wt_gu = (unsigned short*)(ws + 15728640);  // 8192x1024, 64-blk interleave
  unsigned short* wt_down = (unsigned short*)(ws + 32505856);
  unsigned short* audio_bf = (unsigned short*)(ws + 40894464);
  float* mods = (float*)(ws + 42467328);
  unsigned short* x_sa = (unsigned short*)(ws + 42516480);
  unsigned short* qkv = (unsigned short*)(ws + 50905088);
  unsigned short* vt_s = (unsigned short*)(ws + 76070912);
  unsigned short* sa = (unsigned short*)(ws + 84459520);
  unsigned short* xn = (unsigned short*)(ws + 42516480);
  unsigned short* qc = (unsigned short*)(ws + 50905088);
  unsigned short* kvc = (unsigned short*)(ws + 59293696);
  unsigned short* vt_c = (unsigned short*)(ws + 63488000);
  unsigned short* ca = (unsigned short*)(ws + 65585152);
  unsigned short* x_mlp = (unsigned short*)(ws + 42516480);
  unsigned short* hbuf = (unsigned short*)(ws + 50905088);  // 4096 x 4096 bf16 = 32MB

  // weight prep: one launch for all transposes
  WTArgs wa;
  wa.d[0] = {W_qkv, wt_qkv, 1024, 3072, 0, 0, 96 * 32};
  wa.d[1] = {W_sa, wt_sa, 1024, 1024, 0, 0, 32 * 32};
  wa.d[2] = {W_q, wt_q, 1024, 1024, 0, 0, 32 * 32};
  wa.d[3] = {W_kv, wt_kv, 768, 2048, 0, 0, 64 * 24};
  wa.d[4] = {W_ca, wt_ca, 1024, 1024, 0, 0, 32 * 32};
  wa.d[5] = {W_gate, wt_gu, 1024, 4096, 6, 0, 128 * 32};
  wa.d[6] = {W_up, wt_gu, 1024, 4096, 6, 64, 128 * 32};
  wa.d[7] = {W_down, wt_down, 4096, 1024, 0, 0, 32 * 128};
  int total_tiles = 3072 + 1024 + 1024 + 1536 + 1024 + 4096 + 4096 + 4096;
  wtrans_all<<<total_tiles, 256, 0, stream>>>(wa);
  f2bf_copy<<<768, 256, 0, stream>>>(audio, audio_bf, 786432);
  mods_kernel<<<dim3(96, 2), 256, 0, stream>>>(t_mod, adaW, adaB, mods);

  // self-attention block
  rmsnorm_mod<<<4096, 256, 0, stream>>>(x, norm1_w, mods, 0, 1024, x_sa);
  gemm_pipe<3, 128><<<dim3(32, 24), 256, 0, stream>>>(x_sa, wt_qkv, qkv, nullptr, nullptr,
                                                      fcos, fsin, 3072, 1024, 1024);
  vtrans<<<dim3(32, 16, 2), 256, 0, stream>>>(qkv + 2048, vt_s, 3072, 6291456, 2048);
  attn4<<<dim3(32, 16, 2), 256, 0, stream>>>(qkv, 3072, 6291456, qkv + 1024, 3072, 6291456,
                                             vt_s, sa, 1024, 2097152, 2048);
  gemm_pipe<1, 64><<<dim3(64, 8), 256, 0, stream>>>(sa, wt_sa, x_res, x, mods + 2048, nullptr,
                                                    nullptr, 1024, 1024, 1024);

  // cross-attention block
  rmsnorm_mod<<<4096, 256, 0, stream>>>(x_res, norm2_w, nullptr, 0, 0, xn);
  gemm_pipe<0, 64><<<dim3(64, 8), 256, 0, stream>>>(xn, wt_q, qc, nullptr, nullptr, nullptr,
                                                    nullptr, 1024, 1024, 1024);
  gemm_pipe<0, 64><<<dim3(16, 16), 256, 0, stream>>>(audio_bf, wt_kv, kvc, nullptr, nullptr,
                                                     nullptr, nullptr, 2048, 768, 768);
  vtrans<<<dim3(8, 16, 2), 256, 0, stream>>>(kvc + 1024, vt_c, 2048, 1048576, 512);
  attn4<<<dim3(32, 16, 2), 256, 0, stream>>>(qc, 1024, 2097152, kvc, 2048, 1048576, vt_c, ca,
                                             1024, 2097152, 512);
  gemm_pipe<1, 64><<<dim3(64, 8), 256, 0, stream>>>(ca, wt_ca, x_res, x_res, nullptr, nullptr,
                                                    nullptr, 1024, 1024, 1024);

  // MLP block: 256x128 pipelined gate+up with fused swiglu -> hbuf, then pipelined down
  rmsnorm_mod<<<4096, 256, 0, stream>>>(x_res, norm3_w, mods, 3072, 4096, x_mlp);
  gemm256_swiglu<<<1024, 512, 0, stream>>>(x_mlp, wt_gu, hbuf);
  gemm_pipe<1, 64><<<dim3(64, 8), 256, 0, stream>>>(hbuf, wt_down, x_res, x_res, mods + 5120,
                                                    nullptr, nullptr, 1024, 4096, 4096);
}